// Round 4
// baseline (459.818 us; speedup 1.0000x reference)
//
#include <hip/hip_runtime.h>
#include <math.h>

// Problem constants (fixed by setup_inputs)
#define TOKENS 50176   // B*T*H*W = 2*8*56*56
#define NWIN   512     // total windows = B * 256

typedef __attribute__((ext_vector_type(8))) short short8;
typedef __attribute__((ext_vector_type(4))) float f32x4;

// float -> bf16 with round-to-nearest-even
__device__ __forceinline__ unsigned short f2bf(float f) {
    unsigned int u = __builtin_bit_cast(unsigned int, f);
    u += 0x7fffu + ((u >> 16) & 1);
    return (unsigned short)(u >> 16);
}

// async global->LDS, 16B per lane (global_load_lds_dwordx4)
__device__ __forceinline__ void gll16(const void* g, void* l) {
    __builtin_amdgcn_global_load_lds(
        (const __attribute__((address_space(1))) unsigned int*)g,
        (__attribute__((address_space(3))) unsigned int*)l, 16, 0, 0);
}

// Map a window-ordered token index u -> flat (b,t,h,w) index.
// Serves BOTH gather (roll(-)+partition) and scatter (reverse+roll(+)).
__device__ __forceinline__ int win_token_to_flat(int u) {
    int g = u / 98;
    int n = u - g * 98;
    int bb  = g >> 8;
    int rem = g & 255;
    int tb = rem >> 6, hb = (rem >> 3) & 7, wb = rem & 7;
    int dt = n / 49;
    int r2 = n - dt * 49;
    int dh = r2 / 7, dw = r2 - dh * 7;
    int t = tb * 2 + dt, h = hb * 7 + dh, w = wb * 7 + dw;
    int ts = (t + 1) & 7;
    int hs = h + 3; if (hs >= 56) hs -= 56;
    int wsx = w + 3; if (wsx >= 56) wsx -= 56;
    return ((bb * 8 + ts) * 56 + hs) * 56 + wsx;
}

// elementwise fp32 -> bf16 (weights)
__global__ __launch_bounds__(256) void cvt_kernel(
        const float* __restrict__ src, unsigned short* __restrict__ dst, int n) {
    int i = blockIdx.x * 256 + threadIdx.x;
    if (i < n) dst[i] = f2bf(src[i]);
}

// Precompute combined rel-pos bias + shift mask tables:
// bm[cls 8][head 8][row 112][col 112] fp32. cls bits: (tb==3)<<2 | (hb==7)<<1 | (wb==7).
__global__ __launch_bounds__(256) void bm_kernel(
        const float* __restrict__ rpe, float* __restrict__ bm) {
    int i = blockIdx.x * 256 + threadIdx.x;   // 8*8*112*112 = 802816 exact
    int c  = i % 112;
    int t1 = i / 112;
    int r  = t1 % 112;
    int t2 = t1 / 112;
    int head = t2 & 7;
    int cls  = t2 >> 3;
    float val;
    if (c >= 98) {
        val = -1e30f;
    } else if (r >= 98) {
        val = 0.f;
    } else {
        int dt = r / 49, rr = r - dt * 49, dh = rr / 7, dw = rr - dh * 7;
        int dt2 = c / 49, cc = c - dt2 * 49, dh2 = cc / 7, dw2 = cc - dh2 * 7;
        int rt  = (cls & 4) ? (dt  == 0 ? 1 : 2) : 0;
        int rh  = (cls & 2) ? (dh  <  4 ? 1 : 2) : 0;
        int rw  = (cls & 1) ? (dw  <  4 ? 1 : 2) : 0;
        int rt2 = (cls & 4) ? (dt2 == 0 ? 1 : 2) : 0;
        int rh2 = (cls & 2) ? (dh2 <  4 ? 1 : 2) : 0;
        int rw2 = (cls & 1) ? (dw2 <  4 ? 1 : 2) : 0;
        int reg1 = rt * 9 + rh * 3 + rw, reg2 = rt2 * 9 + rh2 * 3 + rw2;
        int idx = (dt - dt2 + 1) * 169 + (dh - dh2 + 6) * 13 + (dw - dw2 + 6);
        val = rpe[idx * 8 + head] + ((reg1 == reg2) ? 0.f : -100.f);
    }
    bm[i] = val;
}

// ---------------------------------------------------------------------------
// Fused LayerNorm + GEMM, row-owner: block owns 64 rows, loops over all NCOLS.
// Phase 1: LN(x rows) -> LDS h tile (bf16, XOR-swizzled: chunk' = chunk^(row&7)
//          -> fragment reads are 2-way bank aliased = free).
// Each wave then hoists its 16 rows' full-K A-fragments into 32 VGPRs (once).
// Phase 2: per 64-col chunk: stage W-chunk via global_load_lds (L2-resident),
//          32 MFMA/wave, epilogue (+bias, EPI 0 = Q-scale qkv / 2 = GELU).
// A rows are read from HBM exactly once; no LN intermediate buffer.
// ---------------------------------------------------------------------------
template<int NCOLS, int EPI, bool GATHER>
__global__ __launch_bounds__(256) void ln_gemm_kernel(
        const float* __restrict__ X, const float* __restrict__ lnw,
        const float* __restrict__ lnb, const unsigned short* __restrict__ W,
        const float* __restrict__ bias, unsigned short* __restrict__ out) {
    __shared__ __attribute__((aligned(16))) unsigned short h[64 * 256];
    __shared__ __attribute__((aligned(16))) unsigned short wbuf[64 * 256];
    int tid = threadIdx.x, wave = tid >> 6, lane = tid & 63;
    int row0 = blockIdx.x * 64;

    // phase 1: LN, 16 rows per wave. lane owns cols [4l, 4l+4).
    float4 gw = *(const float4*)(lnw + lane * 4);
    float4 gb = *(const float4*)(lnb + lane * 4);
    for (int t = 0; t < 16; ++t) {
        int row = wave * 16 + t;
        int token = row0 + row;
        size_t src = GATHER ? (size_t)win_token_to_flat(token) * 256
                            : (size_t)token * 256;
        float4 v = *(const float4*)(X + src + lane * 4);
        float sum = v.x + v.y + v.z + v.w;
#pragma unroll
        for (int o = 32; o > 0; o >>= 1) sum += __shfl_xor(sum, o, 64);
        float mu = sum * (1.f / 256.f);
        float d0 = v.x - mu, d1 = v.y - mu, d2 = v.z - mu, d3 = v.w - mu;
        float var = d0 * d0 + d1 * d1 + d2 * d2 + d3 * d3;
#pragma unroll
        for (int o = 32; o > 0; o >>= 1) var += __shfl_xor(var, o, 64);
        float rstd = rsqrtf(var * (1.f / 256.f) + 1e-5f);
        unsigned long long pk =
              (unsigned long long)f2bf(d0 * rstd * gw.x + gb.x)
            | ((unsigned long long)f2bf(d1 * rstd * gw.y + gb.y) << 16)
            | ((unsigned long long)f2bf(d2 * rstd * gw.z + gb.z) << 32)
            | ((unsigned long long)f2bf(d3 * rstd * gw.w + gb.w) << 48);
        int cp = (lane >> 1) ^ (row & 7);   // 16B-chunk swizzle
        *(unsigned long long*)&h[row * 256 + cp * 8 + (lane & 1) * 4] = pk;
    }

    // hoist A-fragments: own-wave rows only (no barrier needed; wave-ordered DS)
    int fm = lane & 15, fq = lane >> 4;
    int arow = wave * 16 + fm;
    short8 af[8];
#pragma unroll
    for (int kw = 0; kw < 8; ++kw) {
        int c = (kw * 4 + fq) ^ (arow & 7);
        af[kw] = *(const short8*)&h[arow * 256 + c * 8];
    }

    const float qscale = 0.17677669529663687f;
    for (int nc = 0; nc < NCOLS / 64; ++nc) {
        __syncthreads();   // previous chunk's B reads done before restage
        // stage 64x256 weight chunk, swizzled: slot s holds (row=s>>5, c=(s&31)^(row&7))
#pragma unroll
        for (int i = 0; i < 8; ++i) {
            int s = tid + 256 * i;
            int wrow = s >> 5, cp = s & 31;
            int c = cp ^ (wrow & 7);
            gll16(W + (size_t)(nc * 64 + wrow) * 256 + c * 8, wbuf + s * 8);
        }
        __syncthreads();   // vmcnt drain: staged chunk visible
        f32x4 acc[4] = {};
#pragma unroll
        for (int nt = 0; nt < 4; ++nt) {
            int brow = nt * 16 + fm;
#pragma unroll
            for (int kw = 0; kw < 8; ++kw) {
                int c = (kw * 4 + fq) ^ (brow & 7);
                short8 bfr = *(const short8*)&wbuf[brow * 256 + c * 8];
                acc[nt] = __builtin_amdgcn_mfma_f32_16x16x32_bf16(
                    af[kw], bfr, acc[nt], 0, 0, 0);
            }
        }
        // epilogue: C/D layout col=lane&15, row=(lane>>4)*4+v
#pragma unroll
        for (int nt = 0; nt < 4; ++nt) {
            int col = nc * 64 + nt * 16 + fm;
            float b = bias[col];
            size_t obase = (size_t)(row0 + wave * 16 + fq * 4) * NCOLS + col;
#pragma unroll
            for (int v = 0; v < 4; ++v) {
                float val = acc[nt][v] + b;
                if (EPI == 0)
                    val *= (nc < 4) ? qscale : 1.f;   // scale Q block
                else
                    val = 0.5f * val * (1.f + erff(val * 0.70710678118654752f));
                out[obase + (size_t)v * NCOLS] = f2bf(val);
            }
        }
    }
}

// ---------------------------------------------------------------------------
// FC2 + residual: C(TOKENSx256) = A(TOKENSx1024) @ W(256x1024)^T + bias + res.
// Row-owner: block = 64 rows x full N=256 (A fetched once), K-loop 32 iters,
// pair-XOR-swizzled LDS staging (2-way = conflict-free), 4 waves x 64x64 tile.
// ---------------------------------------------------------------------------
__global__ __launch_bounds__(256) void fc2_kernel(
        const unsigned short* __restrict__ A, const unsigned short* __restrict__ W,
        const float* __restrict__ bias, const float* __restrict__ res,
        float* __restrict__ out) {
    __shared__ __attribute__((aligned(16))) unsigned short As[64 * 32];
    __shared__ __attribute__((aligned(16))) unsigned short Bs[256 * 32];
    int tid = threadIdx.x, wave = tid >> 6, lane = tid & 63;
    int fm = lane & 15, fq = lane >> 4;
    int row0 = blockIdx.x * 64;

    f32x4 acc[4][4] = {};   // [mt][nt], wave tile 64 rows x 64 cols

    // staging maps (pair-swizzle): slot = pair*8+idx; idxg = idx^(pair&7);
    // holds (row = pair*2 + (idxg>>2), kchunk = idxg&3)
    int apair = tid >> 3, aidx = tid & 7;
    int aig = aidx ^ (apair & 7);
    const unsigned short* Asrc =
        A + (size_t)(row0 + apair * 2 + (aig >> 2)) * 1024 + (aig & 3) * 8;

    int bslots[4];
    const unsigned short* Bsrc[4];
#pragma unroll
    for (int i = 0; i < 4; ++i) {
        int s = tid + 256 * i;
        int pr = s >> 3, idx = s & 7;
        int ig = idx ^ (pr & 7);
        bslots[i] = s;
        Bsrc[i] = W + (size_t)(pr * 2 + (ig >> 2)) * 1024 + (ig & 3) * 8;
    }

    for (int k0 = 0; k0 < 1024; k0 += 32) {
        __syncthreads();
        gll16(Asrc + k0, As + tid * 8);
#pragma unroll
        for (int i = 0; i < 4; ++i)
            gll16(Bsrc[i] + k0, Bs + bslots[i] * 8);
        __syncthreads();
        short8 afr[4], bfr[4];
#pragma unroll
        for (int mt = 0; mt < 4; ++mt) {
            int r = mt * 16 + fm;
            int idx = (((r & 1) << 2) | fq) ^ ((r >> 1) & 7);
            afr[mt] = *(const short8*)&As[((r >> 1) * 8 + idx) * 8];
        }
#pragma unroll
        for (int nt = 0; nt < 4; ++nt) {
            int r = wave * 64 + nt * 16 + fm;
            int idx = (((r & 1) << 2) | fq) ^ ((r >> 1) & 7);
            bfr[nt] = *(const short8*)&Bs[((r >> 1) * 8 + idx) * 8];
        }
#pragma unroll
        for (int mt = 0; mt < 4; ++mt)
#pragma unroll
            for (int nt = 0; nt < 4; ++nt)
                acc[mt][nt] = __builtin_amdgcn_mfma_f32_16x16x32_bf16(
                    afr[mt], bfr[nt], acc[mt][nt], 0, 0, 0);
    }

#pragma unroll
    for (int nt = 0; nt < 4; ++nt) {
        int col = wave * 64 + nt * 16 + fm;
        float b = bias[col];
#pragma unroll
        for (int mt = 0; mt < 4; ++mt) {
            size_t base = (size_t)(row0 + mt * 16 + fq * 4) * 256 + col;
#pragma unroll
            for (int v = 0; v < 4; ++v) {
                size_t off = base + (size_t)v * 256;
                out[off] = res[off] + acc[mt][nt][v] + b;
            }
        }
    }
}

// proj GEMM (m97 structure): C = A(bf16) @ W^T + bias, scatter + residual, fp32.
__global__ __launch_bounds__(256) void proj_gemm(
        const unsigned short* __restrict__ A, const unsigned short* __restrict__ B,
        const float* __restrict__ bias, const float* __restrict__ res,
        float* __restrict__ C) {
    const int N = 256, K = 256;
    __shared__ __attribute__((aligned(16))) unsigned short Asm[128 * 32];
    __shared__ __attribute__((aligned(16))) unsigned short Bsm[128 * 32];
    int tid = threadIdx.x;
    int wave = tid >> 6, lane = tid & 63;
    int row0 = blockIdx.y * 128, col0 = blockIdx.x * 128;
    int wr = (wave >> 1) * 64;
    int wc = (wave & 1) * 64;

    f32x4 acc[4][4] = {};

    int sr = tid >> 2;
    int sk = (tid & 3) * 8;
    const unsigned short* Ag0 = A + (size_t)(row0 + sr) * K + sk;
    const unsigned short* Ag1 = A + (size_t)(row0 + 64 + sr) * K + sk;
    const unsigned short* Bg0 = B + (size_t)(col0 + sr) * K + sk;
    const unsigned short* Bg1 = B + (size_t)(col0 + 64 + sr) * K + sk;
    unsigned short* Al = Asm + tid * 8;
    unsigned short* Bl = Bsm + tid * 8;

    int fm = lane & 15, fk = (lane >> 4) * 8;

    for (int k0 = 0; k0 < K; k0 += 32) {
        __syncthreads();
        gll16(Ag0 + k0, Al);
        gll16(Ag1 + k0, Al + 64 * 32);
        gll16(Bg0 + k0, Bl);
        gll16(Bg1 + k0, Bl + 64 * 32);
        __syncthreads();
        short8 af[4], bf[4];
#pragma unroll
        for (int t4 = 0; t4 < 4; ++t4) {
            af[t4] = *(const short8*)&Asm[(wr + t4 * 16 + fm) * 32 + fk];
            bf[t4] = *(const short8*)&Bsm[(wc + t4 * 16 + fm) * 32 + fk];
        }
#pragma unroll
        for (int i = 0; i < 4; ++i)
#pragma unroll
            for (int j = 0; j < 4; ++j)
                acc[i][j] = __builtin_amdgcn_mfma_f32_16x16x32_bf16(
                    af[i], bf[j], acc[i][j], 0, 0, 0);
    }

    int crow0 = row0 + wr + (lane >> 4) * 4;
    int ccol0 = col0 + wc + (lane & 15);
    float bj[4];
#pragma unroll
    for (int j = 0; j < 4; ++j) bj[j] = bias[ccol0 + j * 16];

#pragma unroll
    for (int i = 0; i < 4; ++i)
#pragma unroll
        for (int v = 0; v < 4; ++v) {
            int r = crow0 + i * 16 + v;
            size_t base = (size_t)win_token_to_flat(r) * 256 + ccol0;
#pragma unroll
            for (int j = 0; j < 4; ++j)
                C[base + j * 16] = res[base + j * 16] + acc[i][j][v] + bj[j];
        }
}

// MFMA windowed attention: one block per (window, head), 4 waves. (R3, unchanged)
__global__ __launch_bounds__(256) void attn_mfma_kernel(
        const unsigned short* __restrict__ qkv, const float* __restrict__ bm,
        unsigned short* __restrict__ out) {
    __shared__ __attribute__((aligned(16))) unsigned short Vt[32][136];
    __shared__ __attribute__((aligned(16))) unsigned short Pw[4][16][136];
    int blk = blockIdx.x;
    int g = blk >> 3, head = blk & 7;
    int tid = threadIdx.x, wave = tid >> 6, lane = tid & 63;

    for (int i = tid; i < 32 * 30; i += 256) {
        int d = i / 30, c = 98 + (i - d * 30);
        Vt[d][c] = 0;
    }
    const unsigned short* vbase = qkv + (size_t)g * 98 * 768 + 512 + head * 32;
    for (int i = tid; i < 98 * 16; i += 256) {
        int n = i >> 4, dp = i & 15;
        unsigned int val = *(const unsigned int*)(vbase + (size_t)n * 768 + dp * 2);
        Vt[dp * 2][n]     = (unsigned short)val;
        Vt[dp * 2 + 1][n] = (unsigned short)(val >> 16);
    }
    {
        int m = lane >> 2, c = 112 + (lane & 3) * 4;
        *(unsigned long long*)&Pw[wave][m][c] = 0ULL;
    }
    __syncthreads();

    const unsigned short* qbase = qkv + (size_t)g * 98 * 768 + head * 32;
    const unsigned short* kbase = qbase + 256;
    int rem = g & 255;
    int cls = (((rem >> 6) == 3) << 2) | (((((rem >> 3) & 7)) == 7) << 1) | ((rem & 7) == 7);
    const float* bmh = bm + (size_t)(cls * 8 + head) * 112 * 112;

    int fm = lane & 15, fq = lane >> 4;
    int fk = fq * 8;
    unsigned short* obase = out + (size_t)g * 98 * 256 + head * 32;

    for (int s = wave; s < 7; s += 4) {
        int m0 = s * 16;
        int arow = m0 + fm; if (arow > 97) arow = 97;
        short8 af = *(const short8*)(qbase + (size_t)arow * 768 + fk);
        f32x4 S[7];
        f32x4 z = {0.f, 0.f, 0.f, 0.f};
#pragma unroll
        for (int j = 0; j < 7; ++j) {
            int krow = j * 16 + fm; if (krow > 97) krow = 97;
            short8 kf = *(const short8*)(kbase + (size_t)krow * 768 + fk);
            S[j] = __builtin_amdgcn_mfma_f32_16x16x32_bf16(af, kf, z, 0, 0, 0);
        }
        const float* bmrow = bmh + (m0 + fq * 4) * 112 + fm;
#pragma unroll
        for (int j = 0; j < 7; ++j)
#pragma unroll
            for (int v = 0; v < 4; ++v)
                S[j][v] += bmrow[v * 112 + j * 16];
        float inv[4];
#pragma unroll
        for (int v = 0; v < 4; ++v) {
            float m_ = S[0][v];
#pragma unroll
            for (int j = 1; j < 7; ++j) m_ = fmaxf(m_, S[j][v]);
#pragma unroll
            for (int o = 1; o < 16; o <<= 1) m_ = fmaxf(m_, __shfl_xor(m_, o, 64));
            float t = 0.f;
#pragma unroll
            for (int j = 0; j < 7; ++j) { S[j][v] = __expf(S[j][v] - m_); t += S[j][v]; }
#pragma unroll
            for (int o = 1; o < 16; o <<= 1) t += __shfl_xor(t, o, 64);
            inv[v] = 1.f / t;
        }
#pragma unroll
        for (int j = 0; j < 7; ++j)
#pragma unroll
            for (int v = 0; v < 4; ++v)
                Pw[wave][fq * 4 + v][j * 16 + fm] = f2bf(S[j][v]);
        f32x4 O0 = {0.f, 0.f, 0.f, 0.f}, O1 = {0.f, 0.f, 0.f, 0.f};
#pragma unroll
        for (int ks = 0; ks < 4; ++ks) {
            short8 pf = *(const short8*)&Pw[wave][fm][ks * 32 + fk];
            short8 v0 = *(const short8*)&Vt[fm][ks * 32 + fk];
            short8 v1 = *(const short8*)&Vt[16 + fm][ks * 32 + fk];
            O0 = __builtin_amdgcn_mfma_f32_16x16x32_bf16(pf, v0, O0, 0, 0, 0);
            O1 = __builtin_amdgcn_mfma_f32_16x16x32_bf16(pf, v1, O1, 0, 0, 0);
        }
#pragma unroll
        for (int v = 0; v < 4; ++v) {
            int row = m0 + fq * 4 + v;
            if (row < 98) {
                obase[(size_t)row * 256 + fm]      = f2bf(O0[v] * inv[v]);
                obase[(size_t)row * 256 + 16 + fm] = f2bf(O1[v] * inv[v]);
            }
        }
    }
}

extern "C" void kernel_launch(void* const* d_in, const int* in_sizes, int n_in,
                              void* d_out, int out_size, void* d_ws, size_t ws_size,
                              hipStream_t stream) {
    const float* x     = (const float*)d_in[0];
    const float* n1w   = (const float*)d_in[1];
    const float* n1b   = (const float*)d_in[2];
    const float* qkvw  = (const float*)d_in[3];
    const float* qkvb  = (const float*)d_in[4];
    const float* projw = (const float*)d_in[5];
    const float* projb = (const float*)d_in[6];
    const float* rpe   = (const float*)d_in[7];
    const float* n2w   = (const float*)d_in[8];
    const float* n2b   = (const float*)d_in[9];
    const float* fc1w  = (const float*)d_in[10];
    const float* fc1b  = (const float*)d_in[11];
    const float* fc2w  = (const float*)d_in[12];
    const float* fc2b  = (const float*)d_in[13];
    float* out = (float*)d_out;

    // workspace layout
    unsigned short* wqkv  = (unsigned short*)d_ws;            // 768*256 bf16
    unsigned short* wproj = wqkv + 768 * 256;                 // 256*256
    unsigned short* wfc1  = wproj + 256 * 256;                // 1024*256
    unsigned short* wfc2  = wfc1 + 1024 * 256;                // 256*1024
    float* bm = (float*)(wfc2 + 256 * 1024);                  // 8*8*112*112 fp32
    unsigned short* attnO = (unsigned short*)(bm + 8 * 8 * 112 * 112); // TOKENS*256 bf16
    unsigned short* qkv_bf = attnO + (size_t)TOKENS * 256;    // TOKENS*768 bf16
    unsigned short* fc1o = qkv_bf;                            // TOKENS*1024 (aliases dead qkv)

    // 0. bias/mask tables + weight casts
    bm_kernel<<<8 * 8 * 112 * 112 / 256, 256, 0, stream>>>(rpe, bm);
    cvt_kernel<<<(768 * 256 + 255) / 256, 256, 0, stream>>>(qkvw, wqkv, 768 * 256);
    cvt_kernel<<<(256 * 256 + 255) / 256, 256, 0, stream>>>(projw, wproj, 256 * 256);
    cvt_kernel<<<(1024 * 256 + 255) / 256, 256, 0, stream>>>(fc1w, wfc1, 1024 * 256);
    cvt_kernel<<<(256 * 1024 + 255) / 256, 256, 0, stream>>>(fc2w, wfc2, 256 * 1024);

    // 1. fused LN1 + roll/partition gather + QKV GEMM (Q pre-scaled) -> bf16
    ln_gemm_kernel<768, 0, true><<<TOKENS / 64, 256, 0, stream>>>(
        x, n1w, n1b, wqkv, qkvb, qkv_bf);
    // 2. MFMA windowed attention -> bf16
    attn_mfma_kernel<<<NWIN * 8, 256, 0, stream>>>(qkv_bf, bm, attnO);
    // 3. proj + window reverse + roll back + residual -> d_out (x1, fp32)
    proj_gemm<<<dim3(2, TOKENS / 128), 256, 0, stream>>>(
        attnO, wproj, projb, x, out);
    // 4. fused LN2 + FC1 + GELU -> bf16
    ln_gemm_kernel<1024, 2, false><<<TOKENS / 64, 256, 0, stream>>>(
        out, n2w, n2b, wfc1, fc1b, fc1o);
    // 5. FC2 + residual (in place on d_out)
    fc2_kernel<<<TOKENS / 64, 256, 0, stream>>>(fc1o, wfc2, fc2b, out, out);
}

// Round 5
// 432.960 us; speedup vs baseline: 1.0620x; 1.0620x over previous
//
#include <hip/hip_runtime.h>
#include <math.h>

// Problem constants (fixed by setup_inputs)
#define TOKENS 50176   // B*T*H*W = 2*8*56*56
#define NWIN   512     // total windows = B * 256
#define MR     392     // TOKENS/128 row panels (392 % 8 == 0 -> XCD-affine remap)

typedef __attribute__((ext_vector_type(8))) short short8;
typedef __attribute__((ext_vector_type(4))) float f32x4;
typedef __attribute__((ext_vector_type(4))) unsigned short us4;

// float -> bf16 with round-to-nearest-even
__device__ __forceinline__ unsigned short f2bf(float f) {
    unsigned int u = __builtin_bit_cast(unsigned int, f);
    u += 0x7fffu + ((u >> 16) & 1);
    return (unsigned short)(u >> 16);
}

// async global->LDS, 16B per lane (global_load_lds_dwordx4)
__device__ __forceinline__ void gll16(const void* g, void* l) {
    __builtin_amdgcn_global_load_lds(
        (const __attribute__((address_space(1))) unsigned int*)g,
        (__attribute__((address_space(3))) unsigned int*)l, 16, 0, 0);
}

// Map a window-ordered token index u -> flat (b,t,h,w) index.
// Serves BOTH gather (roll(-)+partition) and scatter (reverse+roll(+)).
__device__ __forceinline__ int win_token_to_flat(int u) {
    int g = u / 98;
    int n = u - g * 98;
    int bb  = g >> 8;
    int rem = g & 255;
    int tb = rem >> 6, hb = (rem >> 3) & 7, wb = rem & 7;
    int dt = n / 49;
    int r2 = n - dt * 49;
    int dh = r2 / 7, dw = r2 - dh * 7;
    int t = tb * 2 + dt, h = hb * 7 + dh, w = wb * 7 + dw;
    int ts = (t + 1) & 7;
    int hs = h + 3; if (hs >= 56) hs -= 56;
    int wsx = w + 3; if (wsx >= 56) wsx -= 56;
    return ((bb * 8 + ts) * 56 + hs) * 56 + wsx;
}

// elementwise fp32 -> bf16 (weights)
__global__ __launch_bounds__(256) void cvt_kernel(
        const float* __restrict__ src, unsigned short* __restrict__ dst, int n) {
    int i = blockIdx.x * 256 + threadIdx.x;
    if (i < n) dst[i] = f2bf(src[i]);
}

// Precompute combined rel-pos bias + shift mask tables:
// bm[cls 8][head 8][row 112][col 112] fp32. cls bits: (tb==3)<<2 | (hb==7)<<1 | (wb==7).
__global__ __launch_bounds__(256) void bm_kernel(
        const float* __restrict__ rpe, float* __restrict__ bm) {
    int i = blockIdx.x * 256 + threadIdx.x;   // 8*8*112*112 = 802816 exact
    int c  = i % 112;
    int t1 = i / 112;
    int r  = t1 % 112;
    int t2 = t1 / 112;
    int head = t2 & 7;
    int cls  = t2 >> 3;
    float val;
    if (c >= 98) {
        val = -1e30f;
    } else if (r >= 98) {
        val = 0.f;
    } else {
        int dt = r / 49, rr = r - dt * 49, dh = rr / 7, dw = rr - dh * 7;
        int dt2 = c / 49, cc = c - dt2 * 49, dh2 = cc / 7, dw2 = cc - dh2 * 7;
        int rt  = (cls & 4) ? (dt  == 0 ? 1 : 2) : 0;
        int rh  = (cls & 2) ? (dh  <  4 ? 1 : 2) : 0;
        int rw  = (cls & 1) ? (dw  <  4 ? 1 : 2) : 0;
        int rt2 = (cls & 4) ? (dt2 == 0 ? 1 : 2) : 0;
        int rh2 = (cls & 2) ? (dh2 <  4 ? 1 : 2) : 0;
        int rw2 = (cls & 1) ? (dw2 <  4 ? 1 : 2) : 0;
        int reg1 = rt * 9 + rh * 3 + rw, reg2 = rt2 * 9 + rh2 * 3 + rw2;
        int idx = (dt - dt2 + 1) * 169 + (dh - dh2 + 6) * 13 + (dw - dw2 + 6);
        val = rpe[idx * 8 + head] + ((reg1 == reg2) ? 0.f : -100.f);
    }
    bm[i] = val;
}

// LayerNorm over C=256, one wave per token, 4 tokens/block, bf16 out (packed 8B).
template<bool GATHER>
__global__ __launch_bounds__(256) void ln_kernel(
        const float* __restrict__ x, const float* __restrict__ w,
        const float* __restrict__ b, unsigned short* __restrict__ out) {
    int token = blockIdx.x * 4 + (threadIdx.x >> 6);
    int lane  = threadIdx.x & 63;
    size_t so = GATHER ? (size_t)win_token_to_flat(token) * 256
                       : (size_t)token * 256;
    float4 v = *(const float4*)(x + so + lane * 4);
    float sum = v.x + v.y + v.z + v.w;
#pragma unroll
    for (int o = 32; o > 0; o >>= 1) sum += __shfl_xor(sum, o, 64);
    float mu = sum * (1.f / 256.f);
    float d0 = v.x - mu, d1 = v.y - mu, d2 = v.z - mu, d3 = v.w - mu;
    float var = d0 * d0 + d1 * d1 + d2 * d2 + d3 * d3;
#pragma unroll
    for (int o = 32; o > 0; o >>= 1) var += __shfl_xor(var, o, 64);
    float rstd = rsqrtf(var * (1.f / 256.f) + 1e-5f);
    float4 gw = *(const float4*)(w + lane * 4);
    float4 gb = *(const float4*)(b + lane * 4);
    us4 pk = { f2bf(d0 * rstd * gw.x + gb.x), f2bf(d1 * rstd * gw.y + gb.y),
               f2bf(d2 * rstd * gw.z + gb.z), f2bf(d3 * rstd * gw.w + gb.w) };
    *(us4*)(out + (size_t)token * 256 + lane * 4) = pk;
}

// ---------------------------------------------------------------------------
// bf16 MFMA GEMM v2: C(MxN) = A(MxK) @ B(NxK)^T. 128x128 tile, BK=32,
// 4 waves x (64 tokens x 64 cols). SWAPPED operands: mfma(W-frag, token-frag)
// -> D col = token (lane&15), D rows = 4 consecutive weight cols (fq*4+v)
// -> packed float4 / ushort4 epilogue stores.
// LDS content-swizzle c = cp ^ ((row>>1)&3): fragment ds_read_b128 is 2-way
// bank-aliased (free) instead of 8-way. Swizzle realized via gll16 SOURCE
// address (dest stays wave-uniform base + lane*16, per the m104 constraint).
// Grid is linear with r = bid % MR, c = bid / MR: since MR % 8 == 0, all
// col-blocks of a row panel land on the same XCD (bid%8 heuristic) -> the
// A panel is fetched from HBM once and re-hit in that XCD's L2.
// EPI: 0 = +bias, Q-scale (cols<256), bf16   (qkv)
//      1 = +bias, scatter via map, +res, f32 (proj)
//      2 = +bias, exact GELU, bf16           (fc1)
// ---------------------------------------------------------------------------
template<int EPI>
__global__ __launch_bounds__(256) void gemm_v2(
        const unsigned short* __restrict__ A, const unsigned short* __restrict__ B,
        const float* __restrict__ bias, const float* __restrict__ res,
        void* __restrict__ Cout, int N, int K) {
    __shared__ __attribute__((aligned(16))) unsigned short Asm[128 * 32];
    __shared__ __attribute__((aligned(16))) unsigned short Bsm[128 * 32];
    int tid = threadIdx.x;
    int wave = tid >> 6, lane = tid & 63;
    int bid = blockIdx.x;
    int row0 = (bid % MR) * 128;
    int col0 = (bid / MR) * 128;
    int wr = (wave >> 1) * 64;      // wave token offset in tile
    int wc = (wave & 1) * 64;       // wave col offset in tile

    f32x4 acc[4][4] = {};           // [mt token-frag][nt col-frag]

    // staging: slot s holds (row = s>>2, chunk c = (s&3) ^ ((row>>1)&3));
    // thread t covers slots t (rows 0..63) and 256+t (rows 64..127, same c).
    int srow = tid >> 2;
    int sc = (tid & 3) ^ ((srow >> 1) & 3);
    const unsigned short* Ag0 = A + (size_t)(row0 + srow) * K + sc * 8;
    const unsigned short* Ag1 = A + (size_t)(row0 + 64 + srow) * K + sc * 8;
    const unsigned short* Bg0 = B + (size_t)(col0 + srow) * K + sc * 8;
    const unsigned short* Bg1 = B + (size_t)(col0 + 64 + srow) * K + sc * 8;
    unsigned short* Al0 = Asm + tid * 8;
    unsigned short* Al1 = Asm + (256 + tid) * 8;
    unsigned short* Bl0 = Bsm + tid * 8;
    unsigned short* Bl1 = Bsm + (256 + tid) * 8;

    int fm = lane & 15, fq = lane >> 4;

    for (int k0 = 0; k0 < K; k0 += 32) {
        __syncthreads();
        gll16(Ag0 + k0, Al0);
        gll16(Ag1 + k0, Al1);
        gll16(Bg0 + k0, Bl0);
        gll16(Bg1 + k0, Bl1);
        __syncthreads();
        short8 tf[4], wf[4];
#pragma unroll
        for (int mt = 0; mt < 4; ++mt) {
            int r = wr + mt * 16 + fm;
            tf[mt] = *(const short8*)&Asm[(r * 4 + (fq ^ ((r >> 1) & 3))) * 8];
        }
#pragma unroll
        for (int nt = 0; nt < 4; ++nt) {
            int r = wc + nt * 16 + fm;
            wf[nt] = *(const short8*)&Bsm[(r * 4 + (fq ^ ((r >> 1) & 3))) * 8];
        }
#pragma unroll
        for (int mt = 0; mt < 4; ++mt)
#pragma unroll
            for (int nt = 0; nt < 4; ++nt)
                acc[mt][nt] = __builtin_amdgcn_mfma_f32_16x16x32_bf16(
                    wf[nt], tf[mt], acc[mt][nt], 0, 0, 0);
    }

    // epilogue: lane fm = token-within-16, fq*4+v = col-within-16
    int token0 = row0 + wr + fm;
    int wcol0  = col0 + wc + fq * 4;
    float4 bs[4];
#pragma unroll
    for (int nt = 0; nt < 4; ++nt)
        bs[nt] = *(const float4*)&bias[wcol0 + nt * 16];

#pragma unroll
    for (int mt = 0; mt < 4; ++mt) {
        int token = token0 + mt * 16;
        if (EPI == 1) {
            float* C = (float*)Cout;
            size_t tbase = (size_t)win_token_to_flat(token) * 256;
#pragma unroll
            for (int nt = 0; nt < 4; ++nt) {
                size_t off = tbase + wcol0 + nt * 16;
                float4 r4 = *(const float4*)&res[off];
                float4 o4 = { r4.x + acc[mt][nt][0] + bs[nt].x,
                              r4.y + acc[mt][nt][1] + bs[nt].y,
                              r4.z + acc[mt][nt][2] + bs[nt].z,
                              r4.w + acc[mt][nt][3] + bs[nt].w };
                *(float4*)&C[off] = o4;
            }
        } else {
            unsigned short* C = (unsigned short*)Cout;
            size_t tbase = (size_t)token * N;
#pragma unroll
            for (int nt = 0; nt < 4; ++nt) {
                float v0 = acc[mt][nt][0] + bs[nt].x;
                float v1 = acc[mt][nt][1] + bs[nt].y;
                float v2 = acc[mt][nt][2] + bs[nt].z;
                float v3 = acc[mt][nt][3] + bs[nt].w;
                if (EPI == 0) {
                    float mul = (wcol0 + nt * 16 < 256) ? 0.17677669529663687f : 1.f;
                    v0 *= mul; v1 *= mul; v2 *= mul; v3 *= mul;
                } else {   // EPI == 2: exact GELU
                    v0 = 0.5f * v0 * (1.f + erff(v0 * 0.70710678118654752f));
                    v1 = 0.5f * v1 * (1.f + erff(v1 * 0.70710678118654752f));
                    v2 = 0.5f * v2 * (1.f + erff(v2 * 0.70710678118654752f));
                    v3 = 0.5f * v3 * (1.f + erff(v3 * 0.70710678118654752f));
                }
                us4 pk = { f2bf(v0), f2bf(v1), f2bf(v2), f2bf(v3) };
                *(us4*)&C[tbase + wcol0 + nt * 16] = pk;
            }
        }
    }
}

// ---------------------------------------------------------------------------
// FC2 + residual: C(TOKENSx256) = A(TOKENSx1024) @ W(256x1024)^T + bias + res.
// Row-owner: block = 64 rows x full N=256 (A fetched once), 32 K-iters,
// swizzled LDS, swapped-operand MFMA, float4 epilogue. LDS = 20 KB.
// ---------------------------------------------------------------------------
__global__ __launch_bounds__(256) void fc2_kernel(
        const unsigned short* __restrict__ A, const unsigned short* __restrict__ W,
        const float* __restrict__ bias, const float* __restrict__ res,
        float* __restrict__ out) {
    __shared__ __attribute__((aligned(16))) unsigned short As[64 * 32];
    __shared__ __attribute__((aligned(16))) unsigned short Bs[256 * 32];
    int tid = threadIdx.x, wave = tid >> 6, lane = tid & 63;
    int fm = lane & 15, fq = lane >> 4;
    int row0 = blockIdx.x * 64;

    f32x4 acc[4][4] = {};   // [mt token][nt col], wave tile 64 tokens x 64 cols

    // A staging: slot tid -> (row = tid>>2, chunk c = (tid&3)^((row>>1)&3))
    int srow = tid >> 2;
    int sca = (tid & 3) ^ ((srow >> 1) & 3);
    const unsigned short* Asrc = A + (size_t)(row0 + srow) * 1024 + sca * 8;
    // B staging: 4 slots per thread: s = i*256+tid -> row = s>>2 in [0,256)
    const unsigned short* Bsrc[4];
#pragma unroll
    for (int i = 0; i < 4; ++i) {
        int s = i * 256 + tid;
        int br = s >> 2;
        int c = (s & 3) ^ ((br >> 1) & 3);
        Bsrc[i] = W + (size_t)br * 1024 + c * 8;
    }

    for (int k0 = 0; k0 < 1024; k0 += 32) {
        __syncthreads();
        gll16(Asrc + k0, As + tid * 8);
#pragma unroll
        for (int i = 0; i < 4; ++i)
            gll16(Bsrc[i] + k0, Bs + (i * 256 + tid) * 8);
        __syncthreads();
        short8 tf[4], wf[4];
#pragma unroll
        for (int mt = 0; mt < 4; ++mt) {
            int r = mt * 16 + fm;
            tf[mt] = *(const short8*)&As[(r * 4 + (fq ^ ((r >> 1) & 3))) * 8];
        }
#pragma unroll
        for (int nt = 0; nt < 4; ++nt) {
            int r = wave * 64 + nt * 16 + fm;
            wf[nt] = *(const short8*)&Bs[(r * 4 + (fq ^ ((r >> 1) & 3))) * 8];
        }
#pragma unroll
        for (int mt = 0; mt < 4; ++mt)
#pragma unroll
            for (int nt = 0; nt < 4; ++nt)
                acc[mt][nt] = __builtin_amdgcn_mfma_f32_16x16x32_bf16(
                    wf[nt], tf[mt], acc[mt][nt], 0, 0, 0);
    }

    int wcol0 = wave * 64 + fq * 4;
    float4 bs[4];
#pragma unroll
    for (int nt = 0; nt < 4; ++nt)
        bs[nt] = *(const float4*)&bias[wcol0 + nt * 16];
#pragma unroll
    for (int mt = 0; mt < 4; ++mt) {
        size_t tbase = (size_t)(row0 + mt * 16 + fm) * 256;
#pragma unroll
        for (int nt = 0; nt < 4; ++nt) {
            size_t off = tbase + wcol0 + nt * 16;
            float4 r4 = *(const float4*)&res[off];
            float4 o4 = { r4.x + acc[mt][nt][0] + bs[nt].x,
                          r4.y + acc[mt][nt][1] + bs[nt].y,
                          r4.z + acc[mt][nt][2] + bs[nt].z,
                          r4.w + acc[mt][nt][3] + bs[nt].w };
            *(float4*)&out[off] = o4;
        }
    }
}

// MFMA windowed attention: one block per (window, head), 4 waves. (unchanged)
__global__ __launch_bounds__(256) void attn_mfma_kernel(
        const unsigned short* __restrict__ qkv, const float* __restrict__ bm,
        unsigned short* __restrict__ out) {
    __shared__ __attribute__((aligned(16))) unsigned short Vt[32][136];
    __shared__ __attribute__((aligned(16))) unsigned short Pw[4][16][136];
    int blk = blockIdx.x;
    int g = blk >> 3, head = blk & 7;
    int tid = threadIdx.x, wave = tid >> 6, lane = tid & 63;

    for (int i = tid; i < 32 * 30; i += 256) {
        int d = i / 30, c = 98 + (i - d * 30);
        Vt[d][c] = 0;
    }
    const unsigned short* vbase = qkv + (size_t)g * 98 * 768 + 512 + head * 32;
    for (int i = tid; i < 98 * 16; i += 256) {
        int n = i >> 4, dp = i & 15;
        unsigned int val = *(const unsigned int*)(vbase + (size_t)n * 768 + dp * 2);
        Vt[dp * 2][n]     = (unsigned short)val;
        Vt[dp * 2 + 1][n] = (unsigned short)(val >> 16);
    }
    {
        int m = lane >> 2, c = 112 + (lane & 3) * 4;
        *(unsigned long long*)&Pw[wave][m][c] = 0ULL;
    }
    __syncthreads();

    const unsigned short* qbase = qkv + (size_t)g * 98 * 768 + head * 32;
    const unsigned short* kbase = qbase + 256;
    int rem = g & 255;
    int cls = (((rem >> 6) == 3) << 2) | (((((rem >> 3) & 7)) == 7) << 1) | ((rem & 7) == 7);
    const float* bmh = bm + (size_t)(cls * 8 + head) * 112 * 112;

    int fm = lane & 15, fq = lane >> 4;
    int fk = fq * 8;
    unsigned short* obase = out + (size_t)g * 98 * 256 + head * 32;

    for (int s = wave; s < 7; s += 4) {
        int m0 = s * 16;
        int arow = m0 + fm; if (arow > 97) arow = 97;
        short8 af = *(const short8*)(qbase + (size_t)arow * 768 + fk);
        f32x4 S[7];
        f32x4 z = {0.f, 0.f, 0.f, 0.f};
#pragma unroll
        for (int j = 0; j < 7; ++j) {
            int krow = j * 16 + fm; if (krow > 97) krow = 97;
            short8 kf = *(const short8*)(kbase + (size_t)krow * 768 + fk);
            S[j] = __builtin_amdgcn_mfma_f32_16x16x32_bf16(af, kf, z, 0, 0, 0);
        }
        const float* bmrow = bmh + (m0 + fq * 4) * 112 + fm;
#pragma unroll
        for (int j = 0; j < 7; ++j)
#pragma unroll
            for (int v = 0; v < 4; ++v)
                S[j][v] += bmrow[v * 112 + j * 16];
        float inv[4];
#pragma unroll
        for (int v = 0; v < 4; ++v) {
            float m_ = S[0][v];
#pragma unroll
            for (int j = 1; j < 7; ++j) m_ = fmaxf(m_, S[j][v]);
#pragma unroll
            for (int o = 1; o < 16; o <<= 1) m_ = fmaxf(m_, __shfl_xor(m_, o, 64));
            float t = 0.f;
#pragma unroll
            for (int j = 0; j < 7; ++j) { S[j][v] = __expf(S[j][v] - m_); t += S[j][v]; }
#pragma unroll
            for (int o = 1; o < 16; o <<= 1) t += __shfl_xor(t, o, 64);
            inv[v] = 1.f / t;
        }
#pragma unroll
        for (int j = 0; j < 7; ++j)
#pragma unroll
            for (int v = 0; v < 4; ++v)
                Pw[wave][fq * 4 + v][j * 16 + fm] = f2bf(S[j][v]);
        f32x4 O0 = {0.f, 0.f, 0.f, 0.f}, O1 = {0.f, 0.f, 0.f, 0.f};
#pragma unroll
        for (int ks = 0; ks < 4; ++ks) {
            short8 pf = *(const short8*)&Pw[wave][fm][ks * 32 + fk];
            short8 v0 = *(const short8*)&Vt[fm][ks * 32 + fk];
            short8 v1 = *(const short8*)&Vt[16 + fm][ks * 32 + fk];
            O0 = __builtin_amdgcn_mfma_f32_16x16x32_bf16(pf, v0, O0, 0, 0, 0);
            O1 = __builtin_amdgcn_mfma_f32_16x16x32_bf16(pf, v1, O1, 0, 0, 0);
        }
#pragma unroll
        for (int v = 0; v < 4; ++v) {
            int row = m0 + fq * 4 + v;
            if (row < 98) {
                obase[(size_t)row * 256 + fm]      = f2bf(O0[v] * inv[v]);
                obase[(size_t)row * 256 + 16 + fm] = f2bf(O1[v] * inv[v]);
            }
        }
    }
}

extern "C" void kernel_launch(void* const* d_in, const int* in_sizes, int n_in,
                              void* d_out, int out_size, void* d_ws, size_t ws_size,
                              hipStream_t stream) {
    const float* x     = (const float*)d_in[0];
    const float* n1w   = (const float*)d_in[1];
    const float* n1b   = (const float*)d_in[2];
    const float* qkvw  = (const float*)d_in[3];
    const float* qkvb  = (const float*)d_in[4];
    const float* projw = (const float*)d_in[5];
    const float* projb = (const float*)d_in[6];
    const float* rpe   = (const float*)d_in[7];
    const float* n2w   = (const float*)d_in[8];
    const float* n2b   = (const float*)d_in[9];
    const float* fc1w  = (const float*)d_in[10];
    const float* fc1b  = (const float*)d_in[11];
    const float* fc2w  = (const float*)d_in[12];
    const float* fc2b  = (const float*)d_in[13];
    float* out = (float*)d_out;

    // workspace layout
    unsigned short* wqkv  = (unsigned short*)d_ws;            // 768*256 bf16
    unsigned short* wproj = wqkv + 768 * 256;                 // 256*256
    unsigned short* wfc1  = wproj + 256 * 256;                // 1024*256
    unsigned short* wfc2  = wfc1 + 1024 * 256;                // 256*1024
    float* bm = (float*)(wfc2 + 256 * 1024);                  // 8*8*112*112 fp32
    unsigned short* actA  = (unsigned short*)(bm + 8 * 8 * 112 * 112); // TOKENS*256
    unsigned short* attnO = actA + (size_t)TOKENS * 256;      // TOKENS*256 bf16
    unsigned short* qkv_bf = attnO + (size_t)TOKENS * 256;    // TOKENS*768 bf16
    unsigned short* fc1o = qkv_bf;                            // TOKENS*1024 (aliases dead qkv)

    // 0. bias/mask tables + weight casts
    bm_kernel<<<8 * 8 * 112 * 112 / 256, 256, 0, stream>>>(rpe, bm);
    cvt_kernel<<<(768 * 256 + 255) / 256, 256, 0, stream>>>(qkvw, wqkv, 768 * 256);
    cvt_kernel<<<(256 * 256 + 255) / 256, 256, 0, stream>>>(projw, wproj, 256 * 256);
    cvt_kernel<<<(1024 * 256 + 255) / 256, 256, 0, stream>>>(fc1w, wfc1, 1024 * 256);
    cvt_kernel<<<(256 * 1024 + 255) / 256, 256, 0, stream>>>(fc2w, wfc2, 256 * 1024);

    // 1. LN1 + roll + window partition (gather) -> bf16
    ln_kernel<true><<<TOKENS / 4, 256, 0, stream>>>(x, n1w, n1b, actA);
    // 2. QKV projection -> bf16, Q pre-scaled
    gemm_v2<0><<<MR * 6, 256, 0, stream>>>(actA, wqkv, qkvb, nullptr, qkv_bf, 768, 256);
    // 3. MFMA windowed attention -> bf16
    attn_mfma_kernel<<<NWIN * 8, 256, 0, stream>>>(qkv_bf, bm, attnO);
    // 4. proj + window reverse + roll back + residual -> d_out (x1, fp32)
    gemm_v2<1><<<MR * 2, 256, 0, stream>>>(attnO, wproj, projb, x, out, 256, 256);
    // 5. LN2 -> bf16
    ln_kernel<false><<<TOKENS / 4, 256, 0, stream>>>(out, n2w, n2b, actA);
    // 6. FC1 + GELU -> bf16 (aliases dead qkv buffer)
    gemm_v2<2><<<MR * 8, 256, 0, stream>>>(actA, wfc1, fc1b, nullptr, fc1o, 1024, 256);
    // 7. FC2 + residual (in place on d_out)
    fc2_kernel<<<TOKENS / 64, 256, 0, stream>>>(fc1o, wfc2, fc2b, out, out);
}

// Round 6
// 415.920 us; speedup vs baseline: 1.1055x; 1.0410x over previous
//
#include <hip/hip_runtime.h>
#include <math.h>

// Problem constants (fixed by setup_inputs)
#define TOKENS 50176   // B*T*H*W = 2*8*56*56
#define NWIN   512     // total windows = B * 256
#define MR     392     // TOKENS/128 row panels (392 % 8 == 0 -> XCD-affine remap)

typedef __attribute__((ext_vector_type(8))) short short8;
typedef __attribute__((ext_vector_type(4))) float f32x4;
typedef __attribute__((ext_vector_type(4))) unsigned short us4;

// float -> bf16 with round-to-nearest-even
__device__ __forceinline__ unsigned short f2bf(float f) {
    unsigned int u = __builtin_bit_cast(unsigned int, f);
    u += 0x7fffu + ((u >> 16) & 1);
    return (unsigned short)(u >> 16);
}

// fast GELU: x * sigmoid(x*(1.59577 + 0.0713548*x^2))  (tanh-form identity)
// max |diff vs exact erf-GELU| ~5e-4, far below bf16 output rounding.
__device__ __forceinline__ float fast_gelu(float x) {
    float x2 = x * x;
    float z = x * __builtin_fmaf(x2, 0.0713548162726f, 1.59576912161f);
    float s = __builtin_amdgcn_rcpf(1.f + __expf(-z));
    return x * s;
}

// async global->LDS, 16B per lane (global_load_lds_dwordx4)
__device__ __forceinline__ void gll16(const void* g, void* l) {
    __builtin_amdgcn_global_load_lds(
        (const __attribute__((address_space(1))) unsigned int*)g,
        (__attribute__((address_space(3))) unsigned int*)l, 16, 0, 0);
}

// Map a window-ordered token index u -> flat (b,t,h,w) index.
// Serves BOTH gather (roll(-)+partition) and scatter (reverse+roll(+)).
__device__ __forceinline__ int win_token_to_flat(int u) {
    int g = u / 98;
    int n = u - g * 98;
    int bb  = g >> 8;
    int rem = g & 255;
    int tb = rem >> 6, hb = (rem >> 3) & 7, wb = rem & 7;
    int dt = n / 49;
    int r2 = n - dt * 49;
    int dh = r2 / 7, dw = r2 - dh * 7;
    int t = tb * 2 + dt, h = hb * 7 + dh, w = wb * 7 + dw;
    int ts = (t + 1) & 7;
    int hs = h + 3; if (hs >= 56) hs -= 56;
    int wsx = w + 3; if (wsx >= 56) wsx -= 56;
    return ((bb * 8 + ts) * 56 + hs) * 56 + wsx;
}

// single-launch fp32->bf16 cast of all 4 weight matrices into ws
__global__ __launch_bounds__(256) void cvt_all_kernel(
        const float* __restrict__ qkvw, const float* __restrict__ projw,
        const float* __restrict__ fc1w, const float* __restrict__ fc2w,
        unsigned short* __restrict__ dst) {
    int i = blockIdx.x * 256 + threadIdx.x;   // 786432 total, exact grid
    const float* src;
    int off;
    if (i < 196608)      { src = qkvw;  off = i; }
    else if (i < 262144) { src = projw; off = i - 196608; }
    else if (i < 524288) { src = fc1w;  off = i - 262144; }
    else                 { src = fc2w;  off = i - 524288; }
    dst[i] = f2bf(src[off]);
}

// Precompute combined rel-pos bias + shift mask tables:
// bm[cls 8][head 8][row 112][col 112] fp32. cls bits: (tb==3)<<2 | (hb==7)<<1 | (wb==7).
__global__ __launch_bounds__(256) void bm_kernel(
        const float* __restrict__ rpe, float* __restrict__ bm) {
    int i = blockIdx.x * 256 + threadIdx.x;   // 8*8*112*112 = 802816 exact
    int c  = i % 112;
    int t1 = i / 112;
    int r  = t1 % 112;
    int t2 = t1 / 112;
    int head = t2 & 7;
    int cls  = t2 >> 3;
    float val;
    if (c >= 98) {
        val = -1e30f;
    } else if (r >= 98) {
        val = 0.f;
    } else {
        int dt = r / 49, rr = r - dt * 49, dh = rr / 7, dw = rr - dh * 7;
        int dt2 = c / 49, cc = c - dt2 * 49, dh2 = cc / 7, dw2 = cc - dh2 * 7;
        int rt  = (cls & 4) ? (dt  == 0 ? 1 : 2) : 0;
        int rh  = (cls & 2) ? (dh  <  4 ? 1 : 2) : 0;
        int rw  = (cls & 1) ? (dw  <  4 ? 1 : 2) : 0;
        int rt2 = (cls & 4) ? (dt2 == 0 ? 1 : 2) : 0;
        int rh2 = (cls & 2) ? (dh2 <  4 ? 1 : 2) : 0;
        int rw2 = (cls & 1) ? (dw2 <  4 ? 1 : 2) : 0;
        int reg1 = rt * 9 + rh * 3 + rw, reg2 = rt2 * 9 + rh2 * 3 + rw2;
        int idx = (dt - dt2 + 1) * 169 + (dh - dh2 + 6) * 13 + (dw - dw2 + 6);
        val = rpe[idx * 8 + head] + ((reg1 == reg2) ? 0.f : -100.f);
    }
    bm[i] = val;
}

// LayerNorm over C=256, one wave per token, 4 tokens/block, bf16 out (packed 8B).
template<bool GATHER>
__global__ __launch_bounds__(256) void ln_kernel(
        const float* __restrict__ x, const float* __restrict__ w,
        const float* __restrict__ b, unsigned short* __restrict__ out) {
    int token = blockIdx.x * 4 + (threadIdx.x >> 6);
    int lane  = threadIdx.x & 63;
    size_t so = GATHER ? (size_t)win_token_to_flat(token) * 256
                       : (size_t)token * 256;
    float4 v = *(const float4*)(x + so + lane * 4);
    float sum = v.x + v.y + v.z + v.w;
#pragma unroll
    for (int o = 32; o > 0; o >>= 1) sum += __shfl_xor(sum, o, 64);
    float mu = sum * (1.f / 256.f);
    float d0 = v.x - mu, d1 = v.y - mu, d2 = v.z - mu, d3 = v.w - mu;
    float var = d0 * d0 + d1 * d1 + d2 * d2 + d3 * d3;
#pragma unroll
    for (int o = 32; o > 0; o >>= 1) var += __shfl_xor(var, o, 64);
    float rstd = rsqrtf(var * (1.f / 256.f) + 1e-5f);
    float4 gw = *(const float4*)(w + lane * 4);
    float4 gb = *(const float4*)(b + lane * 4);
    us4 pk = { f2bf(d0 * rstd * gw.x + gb.x), f2bf(d1 * rstd * gw.y + gb.y),
               f2bf(d2 * rstd * gw.z + gb.z), f2bf(d3 * rstd * gw.w + gb.w) };
    *(us4*)(out + (size_t)token * 256 + lane * 4) = pk;
}

// ---------------------------------------------------------------------------
// bf16 MFMA GEMM v2: C(MxN) = A(MxK) @ B(NxK)^T. 128x128 tile, BK=32,
// 4 waves x (64 tokens x 64 cols). Swapped operands: mfma(W-frag, token-frag)
// -> D col = token (lane&15), D rows = 4 consecutive weight cols -> packed
// float4 / ushort4 epilogue stores. LDS content-swizzle c = cp^((row>>1)&3)
// (2-way bank alias = free; realized via gll16 SOURCE address). Grid linear,
// r = bid % MR, c = bid / MR: MR % 8 == 0 keeps all col-blocks of a row panel
// on one XCD -> A panel L2 reuse.
// EPI: 0 = +bias, Q-scale (cols<256), bf16   (qkv)
//      1 = +bias, scatter via map, +res, f32 (proj)
//      2 = +bias, fast GELU, bf16            (fc1)
//      3 = +bias, +res, f32                  (fc2)
// ---------------------------------------------------------------------------
template<int EPI>
__global__ __launch_bounds__(256) void gemm_v2(
        const unsigned short* __restrict__ A, const unsigned short* __restrict__ B,
        const float* __restrict__ bias, const float* __restrict__ res,
        void* __restrict__ Cout, int N, int K) {
    __shared__ __attribute__((aligned(16))) unsigned short Asm[128 * 32];
    __shared__ __attribute__((aligned(16))) unsigned short Bsm[128 * 32];
    int tid = threadIdx.x;
    int wave = tid >> 6, lane = tid & 63;
    int bid = blockIdx.x;
    int row0 = (bid % MR) * 128;
    int col0 = (bid / MR) * 128;
    int wr = (wave >> 1) * 64;      // wave token offset in tile
    int wc = (wave & 1) * 64;       // wave col offset in tile

    f32x4 acc[4][4] = {};           // [mt token-frag][nt col-frag]

    // staging: slot s holds (row = s>>2, chunk c = (s&3) ^ ((row>>1)&3))
    int srow = tid >> 2;
    int sc = (tid & 3) ^ ((srow >> 1) & 3);
    const unsigned short* Ag0 = A + (size_t)(row0 + srow) * K + sc * 8;
    const unsigned short* Ag1 = A + (size_t)(row0 + 64 + srow) * K + sc * 8;
    const unsigned short* Bg0 = B + (size_t)(col0 + srow) * K + sc * 8;
    const unsigned short* Bg1 = B + (size_t)(col0 + 64 + srow) * K + sc * 8;
    unsigned short* Al0 = Asm + tid * 8;
    unsigned short* Al1 = Asm + (256 + tid) * 8;
    unsigned short* Bl0 = Bsm + tid * 8;
    unsigned short* Bl1 = Bsm + (256 + tid) * 8;

    int fm = lane & 15, fq = lane >> 4;

    for (int k0 = 0; k0 < K; k0 += 32) {
        __syncthreads();
        gll16(Ag0 + k0, Al0);
        gll16(Ag1 + k0, Al1);
        gll16(Bg0 + k0, Bl0);
        gll16(Bg1 + k0, Bl1);
        __syncthreads();
        short8 tf[4], wf[4];
#pragma unroll
        for (int mt = 0; mt < 4; ++mt) {
            int r = wr + mt * 16 + fm;
            tf[mt] = *(const short8*)&Asm[(r * 4 + (fq ^ ((r >> 1) & 3))) * 8];
        }
#pragma unroll
        for (int nt = 0; nt < 4; ++nt) {
            int r = wc + nt * 16 + fm;
            wf[nt] = *(const short8*)&Bsm[(r * 4 + (fq ^ ((r >> 1) & 3))) * 8];
        }
#pragma unroll
        for (int mt = 0; mt < 4; ++mt)
#pragma unroll
            for (int nt = 0; nt < 4; ++nt)
                acc[mt][nt] = __builtin_amdgcn_mfma_f32_16x16x32_bf16(
                    wf[nt], tf[mt], acc[mt][nt], 0, 0, 0);
    }

    // epilogue: lane fm = token-within-16, fq*4+v = col-within-16
    int token0 = row0 + wr + fm;
    int wcol0  = col0 + wc + fq * 4;
    float4 bs[4];
#pragma unroll
    for (int nt = 0; nt < 4; ++nt)
        bs[nt] = *(const float4*)&bias[wcol0 + nt * 16];
    float qmul = (EPI == 0 && col0 < 256) ? 0.17677669529663687f : 1.f;

#pragma unroll
    for (int mt = 0; mt < 4; ++mt) {
        int token = token0 + mt * 16;
        if (EPI == 1 || EPI == 3) {
            float* C = (float*)Cout;
            size_t tbase = (EPI == 1)
                ? (size_t)win_token_to_flat(token) * 256
                : (size_t)token * 256;
#pragma unroll
            for (int nt = 0; nt < 4; ++nt) {
                size_t off = tbase + wcol0 + nt * 16;
                float4 r4 = *(const float4*)&res[off];
                float4 o4 = { r4.x + acc[mt][nt][0] + bs[nt].x,
                              r4.y + acc[mt][nt][1] + bs[nt].y,
                              r4.z + acc[mt][nt][2] + bs[nt].z,
                              r4.w + acc[mt][nt][3] + bs[nt].w };
                *(float4*)&C[off] = o4;
            }
        } else {
            unsigned short* C = (unsigned short*)Cout;
            size_t tbase = (size_t)token * N;
#pragma unroll
            for (int nt = 0; nt < 4; ++nt) {
                float v0 = acc[mt][nt][0] + bs[nt].x;
                float v1 = acc[mt][nt][1] + bs[nt].y;
                float v2 = acc[mt][nt][2] + bs[nt].z;
                float v3 = acc[mt][nt][3] + bs[nt].w;
                if (EPI == 0) {
                    v0 *= qmul; v1 *= qmul; v2 *= qmul; v3 *= qmul;
                } else {   // EPI == 2: fast GELU
                    v0 = fast_gelu(v0); v1 = fast_gelu(v1);
                    v2 = fast_gelu(v2); v3 = fast_gelu(v3);
                }
                us4 pk = { f2bf(v0), f2bf(v1), f2bf(v2), f2bf(v3) };
                *(us4*)&C[tbase + wcol0 + nt * 16] = pk;
            }
        }
    }
}

// MFMA windowed attention: one block per (window, head), 4 waves. (unchanged)
__global__ __launch_bounds__(256) void attn_mfma_kernel(
        const unsigned short* __restrict__ qkv, const float* __restrict__ bm,
        unsigned short* __restrict__ out) {
    __shared__ __attribute__((aligned(16))) unsigned short Vt[32][136];
    __shared__ __attribute__((aligned(16))) unsigned short Pw[4][16][136];
    int blk = blockIdx.x;
    int g = blk >> 3, head = blk & 7;
    int tid = threadIdx.x, wave = tid >> 6, lane = tid & 63;

    for (int i = tid; i < 32 * 30; i += 256) {
        int d = i / 30, c = 98 + (i - d * 30);
        Vt[d][c] = 0;
    }
    const unsigned short* vbase = qkv + (size_t)g * 98 * 768 + 512 + head * 32;
    for (int i = tid; i < 98 * 16; i += 256) {
        int n = i >> 4, dp = i & 15;
        unsigned int val = *(const unsigned int*)(vbase + (size_t)n * 768 + dp * 2);
        Vt[dp * 2][n]     = (unsigned short)val;
        Vt[dp * 2 + 1][n] = (unsigned short)(val >> 16);
    }
    {
        int m = lane >> 2, c = 112 + (lane & 3) * 4;
        *(unsigned long long*)&Pw[wave][m][c] = 0ULL;
    }
    __syncthreads();

    const unsigned short* qbase = qkv + (size_t)g * 98 * 768 + head * 32;
    const unsigned short* kbase = qbase + 256;
    int rem = g & 255;
    int cls = (((rem >> 6) == 3) << 2) | (((((rem >> 3) & 7)) == 7) << 1) | ((rem & 7) == 7);
    const float* bmh = bm + (size_t)(cls * 8 + head) * 112 * 112;

    int fm = lane & 15, fq = lane >> 4;
    int fk = fq * 8;
    unsigned short* obase = out + (size_t)g * 98 * 256 + head * 32;

    for (int s = wave; s < 7; s += 4) {
        int m0 = s * 16;
        int arow = m0 + fm; if (arow > 97) arow = 97;
        short8 af = *(const short8*)(qbase + (size_t)arow * 768 + fk);
        f32x4 S[7];
        f32x4 z = {0.f, 0.f, 0.f, 0.f};
#pragma unroll
        for (int j = 0; j < 7; ++j) {
            int krow = j * 16 + fm; if (krow > 97) krow = 97;
            short8 kf = *(const short8*)(kbase + (size_t)krow * 768 + fk);
            S[j] = __builtin_amdgcn_mfma_f32_16x16x32_bf16(af, kf, z, 0, 0, 0);
        }
        const float* bmrow = bmh + (m0 + fq * 4) * 112 + fm;
#pragma unroll
        for (int j = 0; j < 7; ++j)
#pragma unroll
            for (int v = 0; v < 4; ++v)
                S[j][v] += bmrow[v * 112 + j * 16];
        float inv[4];
#pragma unroll
        for (int v = 0; v < 4; ++v) {
            float m_ = S[0][v];
#pragma unroll
            for (int j = 1; j < 7; ++j) m_ = fmaxf(m_, S[j][v]);
#pragma unroll
            for (int o = 1; o < 16; o <<= 1) m_ = fmaxf(m_, __shfl_xor(m_, o, 64));
            float t = 0.f;
#pragma unroll
            for (int j = 0; j < 7; ++j) { S[j][v] = __expf(S[j][v] - m_); t += S[j][v]; }
#pragma unroll
            for (int o = 1; o < 16; o <<= 1) t += __shfl_xor(t, o, 64);
            inv[v] = 1.f / t;
        }
#pragma unroll
        for (int j = 0; j < 7; ++j)
#pragma unroll
            for (int v = 0; v < 4; ++v)
                Pw[wave][fq * 4 + v][j * 16 + fm] = f2bf(S[j][v]);
        f32x4 O0 = {0.f, 0.f, 0.f, 0.f}, O1 = {0.f, 0.f, 0.f, 0.f};
#pragma unroll
        for (int ks = 0; ks < 4; ++ks) {
            short8 pf = *(const short8*)&Pw[wave][fm][ks * 32 + fk];
            short8 v0 = *(const short8*)&Vt[fm][ks * 32 + fk];
            short8 v1 = *(const short8*)&Vt[16 + fm][ks * 32 + fk];
            O0 = __builtin_amdgcn_mfma_f32_16x16x32_bf16(pf, v0, O0, 0, 0, 0);
            O1 = __builtin_amdgcn_mfma_f32_16x16x32_bf16(pf, v1, O1, 0, 0, 0);
        }
#pragma unroll
        for (int v = 0; v < 4; ++v) {
            int row = m0 + fq * 4 + v;
            if (row < 98) {
                obase[(size_t)row * 256 + fm]      = f2bf(O0[v] * inv[v]);
                obase[(size_t)row * 256 + 16 + fm] = f2bf(O1[v] * inv[v]);
            }
        }
    }
}

extern "C" void kernel_launch(void* const* d_in, const int* in_sizes, int n_in,
                              void* d_out, int out_size, void* d_ws, size_t ws_size,
                              hipStream_t stream) {
    const float* x     = (const float*)d_in[0];
    const float* n1w   = (const float*)d_in[1];
    const float* n1b   = (const float*)d_in[2];
    const float* qkvw  = (const float*)d_in[3];
    const float* qkvb  = (const float*)d_in[4];
    const float* projw = (const float*)d_in[5];
    const float* projb = (const float*)d_in[6];
    const float* rpe   = (const float*)d_in[7];
    const float* n2w   = (const float*)d_in[8];
    const float* n2b   = (const float*)d_in[9];
    const float* fc1w  = (const float*)d_in[10];
    const float* fc1b  = (const float*)d_in[11];
    const float* fc2w  = (const float*)d_in[12];
    const float* fc2b  = (const float*)d_in[13];
    float* out = (float*)d_out;

    // workspace layout
    unsigned short* wbase = (unsigned short*)d_ws;
    unsigned short* wqkv  = wbase;                            // 768*256 bf16
    unsigned short* wproj = wqkv + 768 * 256;                 // 256*256
    unsigned short* wfc1  = wproj + 256 * 256;                // 1024*256
    unsigned short* wfc2  = wfc1 + 1024 * 256;                // 256*1024
    float* bm = (float*)(wfc2 + 256 * 1024);                  // 8*8*112*112 fp32
    unsigned short* actA  = (unsigned short*)(bm + 8 * 8 * 112 * 112); // TOKENS*256
    unsigned short* attnO = actA + (size_t)TOKENS * 256;      // TOKENS*256 bf16
    unsigned short* qkv_bf = attnO + (size_t)TOKENS * 256;    // TOKENS*768 bf16
    unsigned short* fc1o = qkv_bf;                            // TOKENS*1024 (aliases dead qkv)

    // 0. bias/mask tables + all weight casts (single launch)
    bm_kernel<<<8 * 8 * 112 * 112 / 256, 256, 0, stream>>>(rpe, bm);
    cvt_all_kernel<<<786432 / 256, 256, 0, stream>>>(qkvw, projw, fc1w, fc2w, wbase);

    // 1. LN1 + roll + window partition (gather) -> bf16
    ln_kernel<true><<<TOKENS / 4, 256, 0, stream>>>(x, n1w, n1b, actA);
    // 2. QKV projection -> bf16, Q pre-scaled
    gemm_v2<0><<<MR * 6, 256, 0, stream>>>(actA, wqkv, qkvb, nullptr, qkv_bf, 768, 256);
    // 3. MFMA windowed attention -> bf16
    attn_mfma_kernel<<<NWIN * 8, 256, 0, stream>>>(qkv_bf, bm, attnO);
    // 4. proj + window reverse + roll back + residual -> d_out (x1, fp32)
    gemm_v2<1><<<MR * 2, 256, 0, stream>>>(attnO, wproj, projb, x, out, 256, 256);
    // 5. LN2 -> bf16
    ln_kernel<false><<<TOKENS / 4, 256, 0, stream>>>(out, n2w, n2b, actA);
    // 6. FC1 + fast GELU -> bf16 (aliases dead qkv buffer)
    gemm_v2<2><<<MR * 8, 256, 0, stream>>>(actA, wfc1, fc1b, nullptr, fc1o, 1024, 256);
    // 7. FC2 + residual (in place on d_out)
    gemm_v2<3><<<MR * 2, 256, 0, stream>>>(fc1o, wfc2, fc2b, out, out, 256, 1024);
}